// Round 4
// baseline (1082.104 us; speedup 1.0000x reference)
//
#include <hip/hip_runtime.h>

// TimeEncoder: out[n, :] = concat(W0[T[n,0]], W1[T[n,1]], W2[T[n,2]], W3[T[n,3]])
// N = 2,000,000 rows; tables (366|24|7|60)x32 fp32 (~58 KB total, cache-resident);
// output [N, 128] fp32 = 1.024 GB streaming write. Write-BW-bound; floor ~168 us.
//
// R2 post-mortem: n_items derived from out_size alone wrote 4x the true output
// (out_size is bytes-sized vs my element assumption), corrupting pristine input
// copies. Fix kept: derive N from in_sizes[0] (T is [N,4] int32), clamp by out_size/4.
// R3 post-mortem: __builtin_nontemporal_store needs a NATIVE vector type, not
// HIP's float4 class. Use ext_vector_type(4).

typedef float f32x4 __attribute__((ext_vector_type(4)));

__global__ __launch_bounds__(256) void time_encoder_kernel(
    const int* __restrict__ T,     // [N, 4] row-major int32
    const float* __restrict__ W0,  // [366, 32]
    const float* __restrict__ W1,  // [24, 32]
    const float* __restrict__ W2,  // [7, 32]
    const float* __restrict__ W3,  // [60, 32]
    f32x4* __restrict__ out,       // f32x4 view of [N, 128]
    int n_items)                   // number of float4 slots = N * 32
{
    const int stride = gridDim.x * blockDim.x;
    const int tid = blockIdx.x * blockDim.x + threadIdx.x;
    const int half = n_items >> 1;

    // Two independent gather->store chains per iteration: doubles memory-level
    // parallelism on the T-load -> W-load dependent chain (latency hiding).
    for (int gid = tid; gid < half; gid += stride) {
        const int g1 = gid + half;

        const int row0 = gid >> 5, slot0 = gid & 31;
        const int row1 = g1  >> 5, slot1 = g1  & 31;
        const int part0 = slot0 >> 3, sub0 = slot0 & 7;
        const int part1 = slot1 >> 3, sub1 = slot1 & 7;

        const int t0 = T[(row0 << 2) + part0];
        const int t1 = T[(row1 << 2) + part1];

        // Predicated pointer select (no divergent branches).
        const float* Wa = (part0 == 0) ? W0 : (part0 == 1) ? W1 : (part0 == 2) ? W2 : W3;
        const float* Wb = (part1 == 0) ? W0 : (part1 == 1) ? W1 : (part1 == 2) ? W2 : W3;

        const f32x4 v0 = *reinterpret_cast<const f32x4*>(Wa + t0 * 32 + (sub0 << 2));
        const f32x4 v1 = *reinterpret_cast<const f32x4*>(Wb + t1 * 32 + (sub1 << 2));

        // Output is write-once, never re-read: nontemporal keeps L2/L3 for
        // the T stream and the tables.
        __builtin_nontemporal_store(v0, out + gid);
        __builtin_nontemporal_store(v1, out + g1);
    }

    // Tail (only if n_items is odd; N*32 is even, this is pure defense).
    for (int gid = (half << 1) + tid; gid < n_items; gid += stride) {
        const int row = gid >> 5, slot = gid & 31;
        const int part = slot >> 3, sub = slot & 7;
        const int t = T[(row << 2) + part];
        const float* W = (part == 0) ? W0 : (part == 1) ? W1 : (part == 2) ? W2 : W3;
        __builtin_nontemporal_store(
            *reinterpret_cast<const f32x4*>(W + t * 32 + (sub << 2)), out + gid);
    }
}

extern "C" void kernel_launch(void* const* d_in, const int* in_sizes, int n_in,
                              void* d_out, int out_size, void* d_ws, size_t ws_size,
                              hipStream_t stream) {
    const int*   T  = (const int*)d_in[0];
    const float* W0 = (const float*)d_in[1];
    const float* W1 = (const float*)d_in[2];
    const float* W2 = (const float*)d_in[3];
    const float* W3 = (const float*)d_in[4];
    f32x4* out = (f32x4*)d_out;

    // True output extent from the INPUT shape: T is [N,4] int32.
    const long long N = (long long)in_sizes[0] / 4;
    const long long n_true = N * 32;                  // float4 slots in [N,128]
    const long long n_out  = (long long)out_size / 4; // if out_size is elements
    long long n_ll = n_true < n_out ? n_true : n_out; // clamp: OOB-impossible
    const int n_items = (int)n_ll;

    const int block = 256;
    const int grid = 8192;  // 2M threads; ~16 iters of 2 items each

    time_encoder_kernel<<<grid, block, 0, stream>>>(T, W0, W1, W2, W3, out, n_items);
}